// Round 1
// baseline (2003.005 us; speedup 1.0000x reference)
//
#include <hip/hip_runtime.h>
#include <cstdint>
#include <cstddef>

// ---------------------------------------------------------------------------
// Tiled fp32 GEMM: C[M,N] = act(A[M,K] @ W[K,N] + bias)
// act: 0 = none, 1 = ELU, 2 = sigmoid
// Requires N % 64 == 0, K % 16 == 0 (true for all shapes here).
// ---------------------------------------------------------------------------
__global__ __launch_bounds__(256)
void gemm_kernel(const float* __restrict__ A, const float* __restrict__ W,
                 const float* __restrict__ bias, float* __restrict__ C,
                 int M, int N, int K, int act)
{
    __shared__ float As[16][65];
    __shared__ float Bs[16][64];
    const int t  = threadIdx.x;
    const int tx = t & 15;       // col group (16)
    const int ty = t >> 4;       // row group (16)
    const int row0 = blockIdx.y * 64;
    const int col0 = blockIdx.x * 64;
    // A-tile load mapping: thread loads A[row0 + (t>>2)][k0 + (t&3)*4 .. +3]
    const int ar = t >> 2;           // 0..63
    const int ak = (t & 3) << 2;     // 0,4,8,12
    // B-tile load mapping
    const int bk = t >> 6;           // 0..3
    const int bn = t & 63;

    float acc[4][4] = {};

    for (int k0 = 0; k0 < K; k0 += 16) {
        int grow = row0 + ar;
        float4 a4 = make_float4(0.f, 0.f, 0.f, 0.f);
        if (grow < M)
            a4 = *reinterpret_cast<const float4*>(A + (size_t)grow * K + k0 + ak);
        As[ak + 0][ar] = a4.x;
        As[ak + 1][ar] = a4.y;
        As[ak + 2][ar] = a4.z;
        As[ak + 3][ar] = a4.w;
        #pragma unroll
        for (int i = 0; i < 4; ++i) {
            int kk = bk + (i << 2);
            Bs[kk][bn] = W[(size_t)(k0 + kk) * N + col0 + bn];
        }
        __syncthreads();
        #pragma unroll
        for (int kk = 0; kk < 16; ++kk) {
            float a[4], b[4];
            #pragma unroll
            for (int i = 0; i < 4; ++i) a[i] = As[kk][ty * 4 + i];
            #pragma unroll
            for (int j = 0; j < 4; ++j) b[j] = Bs[kk][tx * 4 + j];
            #pragma unroll
            for (int i = 0; i < 4; ++i)
                #pragma unroll
                for (int j = 0; j < 4; ++j)
                    acc[i][j] += a[i] * b[j];
        }
        __syncthreads();
    }

    #pragma unroll
    for (int i = 0; i < 4; ++i) {
        int r = row0 + ty * 4 + i;
        if (r >= M) continue;
        float4 v;
        float* vp = &v.x;
        #pragma unroll
        for (int j = 0; j < 4; ++j) {
            int c = col0 + tx * 4 + j;
            float xv = acc[i][j];
            if (bias) xv += bias[c];
            if (act == 1)      xv = xv > 0.f ? xv : expm1f(xv);
            else if (act == 2) xv = 1.f / (1.f + expf(-xv));
            vp[j] = xv;
        }
        *reinterpret_cast<float4*>(C + (size_t)r * N + col0 + tx * 4) = v;
    }
}

// ---------------------------------------------------------------------------
// Edge pass 1: attention logits + softmax denominator.
// One thread per (edge, head). p[e*4+h] = exp(e_eh); s[dst*4+h] += p.
// No max-subtraction: alpha = p/s is mathematically identical; |e| is small.
// ---------------------------------------------------------------------------
__global__ __launch_bounds__(256)
void edge_attn(const float* __restrict__ xl, const float* __restrict__ xr,
               const int* __restrict__ ei, const float* __restrict__ att,
               float* __restrict__ p, float* __restrict__ s,
               int E, int Etot)
{
    int tid = blockIdx.x * 256 + threadIdx.x;
    if (tid >= Etot * 4) return;
    int idx = tid >> 2;
    int h   = tid & 3;
    int src, dst;
    if (idx < E) { src = ei[idx]; dst = ei[E + idx]; }
    else         { src = dst = idx - E; }

    const float* pl = xl + (size_t)src * 128 + h * 32;
    const float* pr = xr + (size_t)dst * 128 + h * 32;
    const float* pa = att + h * 32;
    float e = 0.f;
    #pragma unroll
    for (int c = 0; c < 32; c += 4) {
        float4 a = *reinterpret_cast<const float4*>(pl + c);
        float4 b = *reinterpret_cast<const float4*>(pr + c);
        float4 w = *reinterpret_cast<const float4*>(pa + c);
        float z;
        z = a.x + b.x; z = z > 0.f ? z : 0.2f * z; e += w.x * z;
        z = a.y + b.y; z = z > 0.f ? z : 0.2f * z; e += w.y * z;
        z = a.z + b.z; z = z > 0.f ? z : 0.2f * z; e += w.z * z;
        z = a.w + b.w; z = z > 0.f ? z : 0.2f * z; e += w.w * z;
    }
    float pe = expf(e);
    p[(size_t)idx * 4 + h] = pe;
    atomicAdd(s + (size_t)dst * 4 + h, pe);
}

// ---------------------------------------------------------------------------
// Edge pass 2: weighted aggregation. One thread per (edge, channel v=0..127).
// out[dst][v] += xl[src][v] * (p[e][h]/s[dst][h])
// ---------------------------------------------------------------------------
__global__ __launch_bounds__(256)
void edge_aggr(const float* __restrict__ xl, const int* __restrict__ ei,
               const float* __restrict__ p, const float* __restrict__ s,
               float* __restrict__ out, int E, int Etot)
{
    long long tid = (long long)blockIdx.x * 256 + threadIdx.x;
    if (tid >= (long long)Etot * 128) return;
    int idx = (int)(tid >> 7);
    int v   = (int)(tid & 127);
    int h   = v >> 5;
    int src, dst;
    if (idx < E) { src = ei[idx]; dst = ei[E + idx]; }
    else         { src = dst = idx - E; }
    float alpha = p[(size_t)idx * 4 + h] / s[(size_t)dst * 4 + h];
    atomicAdd(out + (size_t)dst * 128 + v, xl[(size_t)src * 128 + v] * alpha);
}

// ---------------------------------------------------------------------------
// Elementwise: h = elu(h + b[v]) over N*128
// ---------------------------------------------------------------------------
__global__ __launch_bounds__(256)
void bias_elu(float* __restrict__ h, const float* __restrict__ b, int total)
{
    int i = blockIdx.x * 256 + threadIdx.x;
    if (i >= total) return;
    float x = h[i] + b[i & 127];
    h[i] = x > 0.f ? x : expm1f(x);
}

// ---------------------------------------------------------------------------
extern "C" void kernel_launch(void* const* d_in, const int* in_sizes, int n_in,
                              void* d_out, int out_size, void* d_ws, size_t ws_size,
                              hipStream_t stream)
{
    const float* x    = (const float*)d_in[0];
    const int*   ei   = (const int*)  d_in[1];
    const float* Wl1  = (const float*)d_in[2];
    const float* Wr1  = (const float*)d_in[3];
    const float* att1 = (const float*)d_in[4];
    const float* b1   = (const float*)d_in[5];
    const float* Wl2  = (const float*)d_in[6];
    const float* Wr2  = (const float*)d_in[7];
    const float* att2 = (const float*)d_in[8];
    const float* b2   = (const float*)d_in[9];
    const float* W1   = (const float*)d_in[10];
    const float* bb1  = (const float*)d_in[11];
    const float* W2   = (const float*)d_in[12];
    const float* bb2  = (const float*)d_in[13];
    const float* W3   = (const float*)d_in[14];
    const float* bb3  = (const float*)d_in[15];
    float* out = (float*)d_out;

    const int N    = in_sizes[0] / 128;
    const int E    = in_sizes[1] / 2;
    const int Etot = E + N;

    // workspace layout (floats)
    float* ws = (float*)d_ws;
    size_t o = 0;
    float* xl   = ws + o; o += (size_t)N * 128;
    float* xr   = ws + o; o += (size_t)N * 128;
    float* h1   = ws + o; o += (size_t)N * 128;
    float* p    = ws + o; o += (size_t)Etot * 4;
    float* sden = ws + o; o += (size_t)N * 4;
    float* h2   = ws + o; o += (size_t)N * 128;

    dim3 blk(256);
    auto gemm = [&](const float* A, const float* Wm, const float* bias, float* C,
                    int M, int Nn, int K, int act) {
        dim3 grid(Nn / 64, (M + 63) / 64);
        hipLaunchKernelGGL(gemm_kernel, grid, blk, 0, stream, A, Wm, bias, C, M, Nn, K, act);
    };

    const int e1_blocks = (Etot * 4 + 255) / 256;
    const long long e2_threads = (long long)Etot * 128;
    const int e2_blocks = (int)((e2_threads + 255) / 256);
    const int ew_blocks = (N * 128 + 255) / 256;

    // ---- conv1 ----
    gemm(x, Wl1, nullptr, xl, N, 128, 128, 0);
    gemm(x, Wr1, nullptr, xr, N, 128, 128, 0);
    hipMemsetAsync(sden, 0, (size_t)N * 4 * sizeof(float), stream);
    hipMemsetAsync(h1,   0, (size_t)N * 128 * sizeof(float), stream);
    hipLaunchKernelGGL(edge_attn, dim3(e1_blocks), blk, 0, stream, xl, xr, ei, att1, p, sden, E, Etot);
    hipLaunchKernelGGL(edge_aggr, dim3(e2_blocks), blk, 0, stream, xl, ei, p, sden, h1, E, Etot);
    hipLaunchKernelGGL(bias_elu,  dim3(ew_blocks), blk, 0, stream, h1, b1, N * 128);

    // ---- conv2 ----
    gemm(h1, Wl2, nullptr, xl, N, 128, 128, 0);
    gemm(h1, Wr2, nullptr, xr, N, 128, 128, 0);
    hipMemsetAsync(sden, 0, (size_t)N * 4 * sizeof(float), stream);
    hipMemsetAsync(h2,   0, (size_t)N * 128 * sizeof(float), stream);
    hipLaunchKernelGGL(edge_attn, dim3(e1_blocks), blk, 0, stream, xl, xr, ei, att2, p, sden, E, Etot);
    hipLaunchKernelGGL(edge_aggr, dim3(e2_blocks), blk, 0, stream, xl, ei, p, sden, h2, E, Etot);
    hipLaunchKernelGGL(bias_elu,  dim3(ew_blocks), blk, 0, stream, h2, b2, N * 128);

    // ---- MLP head (chunked; scratch reuses dead conv buffers at ws base) ----
    const int CHUNK = 16384;
    float* t1 = ws;                           // CHUNK*640 floats
    float* t2 = ws + (size_t)CHUNK * 640;     // CHUNK*320 floats
    for (int c0 = 0; c0 < N; c0 += CHUNK) {
        int cm = (N - c0) < CHUNK ? (N - c0) : CHUNK;
        gemm(h2 + (size_t)c0 * 128, W1, bb1, t1, cm, 640, 128, 1);
        gemm(t1, W2, bb2, t2, cm, 320, 640, 1);
        gemm(t2, W3, bb3, out + (size_t)c0 * 64, cm, 64, 320, 2);
    }
}

// Round 2
// 1178.789 us; speedup vs baseline: 1.6992x; 1.6992x over previous
//
#include <hip/hip_runtime.h>
#include <cstdint>
#include <cstddef>

// ---------------------------------------------------------------------------
// Tiled fp32 GEMM: C[M,N] = act(A[M,K] @ W[K,N] + bias)
// act: 0 = none, 1 = ELU, 2 = sigmoid
// Requires N % 64 == 0, K % 16 == 0 (true for all shapes here).
// ---------------------------------------------------------------------------
__global__ __launch_bounds__(256)
void gemm_kernel(const float* __restrict__ A, const float* __restrict__ W,
                 const float* __restrict__ bias, float* __restrict__ C,
                 int M, int N, int K, int act)
{
    __shared__ float As[16][65];
    __shared__ float Bs[16][64];
    const int t  = threadIdx.x;
    const int tx = t & 15;
    const int ty = t >> 4;
    const int row0 = blockIdx.y * 64;
    const int col0 = blockIdx.x * 64;
    const int ar = t >> 2;
    const int ak = (t & 3) << 2;
    const int bk = t >> 6;
    const int bn = t & 63;

    float acc[4][4] = {};

    for (int k0 = 0; k0 < K; k0 += 16) {
        int grow = row0 + ar;
        float4 a4 = make_float4(0.f, 0.f, 0.f, 0.f);
        if (grow < M)
            a4 = *reinterpret_cast<const float4*>(A + (size_t)grow * K + k0 + ak);
        As[ak + 0][ar] = a4.x;
        As[ak + 1][ar] = a4.y;
        As[ak + 2][ar] = a4.z;
        As[ak + 3][ar] = a4.w;
        #pragma unroll
        for (int i = 0; i < 4; ++i) {
            int kk = bk + (i << 2);
            Bs[kk][bn] = W[(size_t)(k0 + kk) * N + col0 + bn];
        }
        __syncthreads();
        #pragma unroll
        for (int kk = 0; kk < 16; ++kk) {
            float a[4], b[4];
            #pragma unroll
            for (int i = 0; i < 4; ++i) a[i] = As[kk][ty * 4 + i];
            #pragma unroll
            for (int j = 0; j < 4; ++j) b[j] = Bs[kk][tx * 4 + j];
            #pragma unroll
            for (int i = 0; i < 4; ++i)
                #pragma unroll
                for (int j = 0; j < 4; ++j)
                    acc[i][j] = fmaf(a[i], b[j], acc[i][j]);
        }
        __syncthreads();
    }

    #pragma unroll
    for (int i = 0; i < 4; ++i) {
        int r = row0 + ty * 4 + i;
        if (r >= M) continue;
        float4 v;
        float* vp = &v.x;
        #pragma unroll
        for (int j = 0; j < 4; ++j) {
            int c = col0 + tx * 4 + j;
            float xv = acc[i][j];
            if (bias) xv += bias[c];
            if (act == 1)      xv = xv > 0.f ? xv : expm1f(xv);
            else if (act == 2) xv = 1.f / (1.f + expf(-xv));
            vp[j] = xv;
        }
        *reinterpret_cast<float4*>(C + (size_t)r * N + col0 + tx * 4) = v;
    }
}

// ---------------------------------------------------------------------------
// CSR build: histogram -> exclusive scan -> scatter (dst-bucketed src lists)
// ---------------------------------------------------------------------------
__global__ __launch_bounds__(256)
void histo_kernel(const int* __restrict__ ei, int E, int Etot, int* __restrict__ deg)
{
    int e = blockIdx.x * 256 + threadIdx.x;
    if (e >= Etot) return;
    int dst = (e < E) ? ei[E + e] : (e - E);
    atomicAdd(&deg[dst], 1);
}

// 1024 elements per block, 256 threads x 4
__global__ __launch_bounds__(256)
void scan1_kernel(const int* __restrict__ deg, int* __restrict__ off,
                  int* __restrict__ bsum, int N)
{
    __shared__ int sh[256];
    int base = blockIdx.x * 1024;
    int t = threadIdx.x;
    int v[4]; int s = 0;
    #pragma unroll
    for (int i = 0; i < 4; ++i) {
        int idx = base + t * 4 + i;
        v[i] = (idx < N) ? deg[idx] : 0;
        s += v[i];
    }
    sh[t] = s;
    __syncthreads();
    for (int d = 1; d < 256; d <<= 1) {
        int x = 0;
        if (t >= d) x = sh[t - d];
        __syncthreads();
        if (t >= d) sh[t] += x;
        __syncthreads();
    }
    int excl = (t > 0) ? sh[t - 1] : 0;
    #pragma unroll
    for (int i = 0; i < 4; ++i) {
        int idx = base + t * 4 + i;
        if (idx < N) off[idx] = excl;
        excl += v[i];
    }
    if (t == 255) bsum[blockIdx.x] = sh[255];
}

__global__ void scan2_kernel(int* __restrict__ bsum, int nb, int* __restrict__ off_last)
{
    if (threadIdx.x == 0) {
        int run = 0;
        for (int i = 0; i < nb; ++i) { int v = bsum[i]; bsum[i] = run; run += v; }
        *off_last = run;   // == Etot
    }
}

__global__ __launch_bounds__(256)
void scan3_kernel(int* __restrict__ off, const int* __restrict__ bsum, int N)
{
    int i = blockIdx.x * 256 + threadIdx.x;
    if (i < N) off[i] += bsum[i >> 10];
}

__global__ __launch_bounds__(256)
void scatter_kernel(const int* __restrict__ ei, int E, int Etot,
                    const int* __restrict__ off, int* __restrict__ cnt,
                    int* __restrict__ csrc)
{
    int e = blockIdx.x * 256 + threadIdx.x;
    if (e >= Etot) return;
    int src, dst;
    if (e < E) { src = ei[e]; dst = ei[E + e]; }
    else       { src = dst = e - E; }
    int pos = off[dst] + atomicAdd(&cnt[dst], 1);
    csrc[pos] = src;
}

// ---------------------------------------------------------------------------
// Fused GATv2 edge pass: one wave per destination node.
// Lane l holds channels v=l and v=l+64. Heads map onto 32-lane groups:
// reg0 -> heads 0/1, reg1 -> heads 2/3. Per edge: gather xl[src],
// logit via 5-step shfl_xor reduce, p=exp(e), acc += p*xl, s += p.
// Epilogue: out = elu(acc/s + bias). No atomics, no intermediate buffers.
// ---------------------------------------------------------------------------
__global__ __launch_bounds__(256)
void gat_fused(const float* __restrict__ xl, const float* __restrict__ xr,
               const int* __restrict__ off, const int* __restrict__ csrc,
               const float* __restrict__ att, const float* __restrict__ bias,
               float* __restrict__ out, int N)
{
    const int wave = threadIdx.x >> 6;
    const int lane = threadIdx.x & 63;
    const int node = blockIdx.x * 4 + wave;
    if (node >= N) return;

    const float a0 = att[lane];
    const float a1 = att[lane + 64];
    const float xr0 = xr[(size_t)node * 128 + lane];
    const float xr1 = xr[(size_t)node * 128 + lane + 64];

    float acc0 = 0.f, acc1 = 0.f, s0 = 0.f, s1 = 0.f;
    const int beg = off[node];
    const int end = off[node + 1];

    for (int e = beg; e < end; ++e) {
        int src = csrc[e];
        const float* px = xl + (size_t)src * 128;
        float x0 = px[lane];
        float x1 = px[lane + 64];
        float z0 = x0 + xr0; z0 = z0 > 0.f ? z0 : 0.2f * z0; z0 *= a0;
        float z1 = x1 + xr1; z1 = z1 > 0.f ? z1 : 0.2f * z1; z1 *= a1;
        #pragma unroll
        for (int m = 1; m < 32; m <<= 1) {
            z0 += __shfl_xor(z0, m, 64);
            z1 += __shfl_xor(z1, m, 64);
        }
        float p0 = __expf(z0);
        float p1 = __expf(z1);
        s0 += p0; s1 += p1;
        acc0 = fmaf(p0, x0, acc0);
        acc1 = fmaf(p1, x1, acc1);
    }

    float v0 = acc0 / s0 + bias[lane];
    float v1 = acc1 / s1 + bias[lane + 64];
    v0 = v0 > 0.f ? v0 : expm1f(v0);
    v1 = v1 > 0.f ? v1 : expm1f(v1);
    out[(size_t)node * 128 + lane]      = v0;
    out[(size_t)node * 128 + lane + 64] = v1;
}

// ---------------------------------------------------------------------------
extern "C" void kernel_launch(void* const* d_in, const int* in_sizes, int n_in,
                              void* d_out, int out_size, void* d_ws, size_t ws_size,
                              hipStream_t stream)
{
    const float* x    = (const float*)d_in[0];
    const int*   ei   = (const int*)  d_in[1];
    const float* Wl1  = (const float*)d_in[2];
    const float* Wr1  = (const float*)d_in[3];
    const float* att1 = (const float*)d_in[4];
    const float* b1   = (const float*)d_in[5];
    const float* Wl2  = (const float*)d_in[6];
    const float* Wr2  = (const float*)d_in[7];
    const float* att2 = (const float*)d_in[8];
    const float* b2   = (const float*)d_in[9];
    const float* W1   = (const float*)d_in[10];
    const float* bb1  = (const float*)d_in[11];
    const float* W2   = (const float*)d_in[12];
    const float* bb2  = (const float*)d_in[13];
    const float* W3   = (const float*)d_in[14];
    const float* bb3  = (const float*)d_in[15];
    float* out = (float*)d_out;

    const int N    = in_sizes[0] / 128;
    const int E    = in_sizes[1] / 2;
    const int Etot = E + N;

    // workspace layout (floats / ints)
    float* ws = (float*)d_ws;
    size_t o = 0;
    float* xl = ws + o; o += (size_t)N * 128;   // also MLP t1 overlay
    float* xr = ws + o; o += (size_t)N * 128;
    float* h1 = ws + o; o += (size_t)N * 128;   // MLP t2 overlays tail of xr + h1
    float* h2 = ws + o; o += (size_t)N * 128;
    int* ip   = (int*)(ws + o);
    int* off  = ip;                 ip += N + 1;
    int* bsum = ip;                 ip += 64;
    int* deg  = ip;                 ip += N;     // reused as cnt for scatter
    int* csrc = ip;                 ip += Etot;

    dim3 blk(256);
    auto gemm = [&](const float* A, const float* Wm, const float* bias, float* C,
                    int M, int Nn, int K, int act) {
        dim3 grid(Nn / 64, (M + 63) / 64);
        hipLaunchKernelGGL(gemm_kernel, grid, blk, 0, stream, A, Wm, bias, C, M, Nn, K, act);
    };

    const int eb  = (Etot + 255) / 256;
    const int nb  = (N + 1023) / 1024;
    const int nb2 = (N + 255) / 256;
    const int gatb = (N + 3) / 4;

    // ---- build CSR (once; reused by both convs) ----
    hipMemsetAsync(deg, 0, (size_t)N * sizeof(int), stream);
    hipLaunchKernelGGL(histo_kernel, dim3(eb), blk, 0, stream, ei, E, Etot, deg);
    hipLaunchKernelGGL(scan1_kernel, dim3(nb), blk, 0, stream, deg, off, bsum, N);
    hipLaunchKernelGGL(scan2_kernel, dim3(1), dim3(64), 0, stream, bsum, nb, off + N);
    hipLaunchKernelGGL(scan3_kernel, dim3(nb2), blk, 0, stream, off, bsum, N);
    hipMemsetAsync(deg, 0, (size_t)N * sizeof(int), stream);  // -> cnt
    hipLaunchKernelGGL(scatter_kernel, dim3(eb), blk, 0, stream, ei, E, Etot, off, deg, csrc);

    // ---- conv1 ----
    gemm(x, Wl1, nullptr, xl, N, 128, 128, 0);
    gemm(x, Wr1, nullptr, xr, N, 128, 128, 0);
    hipLaunchKernelGGL(gat_fused, dim3(gatb), blk, 0, stream, xl, xr, off, csrc, att1, b1, h1, N);

    // ---- conv2 ----
    gemm(h1, Wl2, nullptr, xl, N, 128, 128, 0);
    gemm(h1, Wr2, nullptr, xr, N, 128, 128, 0);
    hipLaunchKernelGGL(gat_fused, dim3(gatb), blk, 0, stream, xl, xr, off, csrc, att2, b2, h2, N);

    // ---- MLP head (chunked; scratch overlays dead conv buffers) ----
    const int CHUNK = 16384;
    float* t1 = ws;                           // CHUNK*640 floats (xl+xr region)
    float* t2 = ws + (size_t)CHUNK * 640;     // CHUNK*320 floats
    for (int c0 = 0; c0 < N; c0 += CHUNK) {
        int cm = (N - c0) < CHUNK ? (N - c0) : CHUNK;
        gemm(h2 + (size_t)c0 * 128, W1, bb1, t1, cm, 640, 128, 1);
        gemm(t1, W2, bb2, t2, cm, 320, 640, 1);
        gemm(t2, W3, bb3, out + (size_t)c0 * 64, cm, 64, 320, 2);
    }
}

// Round 3
// 1005.079 us; speedup vs baseline: 1.9929x; 1.1728x over previous
//
#include <hip/hip_runtime.h>
#include <cstdint>
#include <cstddef>

typedef __attribute__((ext_vector_type(8))) short short8;
typedef __attribute__((ext_vector_type(4))) float f32x4;
typedef unsigned short u16;

// round-to-nearest-even bf16 split: v ~= hi + lo
__device__ __forceinline__ void bf16split(float v, u16& h, u16& l)
{
    union { float f; unsigned u; } a; a.f = v;
    unsigned r = (a.u + 0x7fffu + ((a.u >> 16) & 1u)) & 0xffff0000u;
    h = (u16)(r >> 16);
    union { unsigned u; float f; } b; b.u = r;
    float res = v - b.f;
    union { float f; unsigned u; } c; c.f = res;
    l = (u16)((c.u + 0x7fffu + ((c.u >> 16) & 1u)) >> 16);
}

// ---------------------------------------------------------------------------
// Split-bf16 MFMA GEMM: C[M,N] = act(A @ W + bias), A=[M,K] as hi/lo bf16
// planes, W given pre-transposed [N,K] as hi/lo bf16 planes.
// C = Ah*Wh + Ah*Wl + Al*Wh (fp32 MFMA accum). Output: fp32 (Cf) or
// hi/lo bf16 planes (Ch/Cl). act: 0=none 1=ELU 2=sigmoid.
// Tile: BM=128, BN=64, BK=64; 256 threads (4 waves), wave -> 64x32.
// Requires N%64==0, K%64==0.
// ---------------------------------------------------------------------------
#define BM 128
#define BN 64
#define BK 64

__global__ __launch_bounds__(256)
void gemm_mfma(const u16* __restrict__ Ah, const u16* __restrict__ Al,
               const u16* __restrict__ Bh, const u16* __restrict__ Bl,
               const float* __restrict__ bias,
               float* __restrict__ Cf, u16* __restrict__ Ch, u16* __restrict__ Cl,
               int M, int N, int K, int act)
{
    __shared__ __align__(16) u16 sA[2][BM * BK];
    __shared__ __align__(16) u16 sB[2][BN * BK];
    const int t = threadIdx.x;
    const int w = t >> 6, lane = t & 63;
    const int lr = lane & 15, lg = lane >> 4;
    const int row0 = blockIdx.y * BM, col0 = blockIdx.x * BN;
    const int rb = (w & 1) * 64, cb = (w >> 1) * 32;

    f32x4 acc[4][2];
    #pragma unroll
    for (int m = 0; m < 4; ++m)
        #pragma unroll
        for (int n = 0; n < 2; ++n) acc[m][n] = (f32x4)0.f;

    for (int k0 = 0; k0 < K; k0 += BK) {
        // stage A tiles (hi/lo), XOR-swizzled at 16B granularity
        #pragma unroll
        for (int i = 0; i < 4; ++i) {
            int id = t + 256 * i;
            int row = id >> 3, kc = id & 7;
            int grow = row0 + row;
            uint4 vh = make_uint4(0, 0, 0, 0), vl = vh;
            if (grow < M) {
                size_t g = (size_t)grow * K + k0 + kc * 8;
                vh = *(const uint4*)(Ah + g);
                vl = *(const uint4*)(Al + g);
            }
            int idx = row * 64 + ((kc ^ (row & 7)) << 3);
            *(uint4*)&sA[0][idx] = vh;
            *(uint4*)&sA[1][idx] = vl;
        }
        // stage B tiles (hi/lo) from transposed weights [N,K]
        #pragma unroll
        for (int i = 0; i < 2; ++i) {
            int id = t + 256 * i;
            int col = id >> 3, kc = id & 7;
            size_t g = (size_t)(col0 + col) * K + k0 + kc * 8;
            uint4 vh = *(const uint4*)(Bh + g);
            uint4 vl = *(const uint4*)(Bl + g);
            int idx = col * 64 + ((kc ^ (col & 7)) << 3);
            *(uint4*)&sB[0][idx] = vh;
            *(uint4*)&sB[1][idx] = vl;
        }
        __syncthreads();
        #pragma unroll
        for (int kk = 0; kk < 2; ++kk) {
            short8 ah[4], al[4], bh[2], bl[2];
            #pragma unroll
            for (int m = 0; m < 4; ++m) {
                int row = rb + m * 16 + lr;
                int idx = row * 64 + (((kk * 4 + lg) ^ (lr & 7)) << 3);
                ah[m] = *(const short8*)&sA[0][idx];
                al[m] = *(const short8*)&sA[1][idx];
            }
            #pragma unroll
            for (int n = 0; n < 2; ++n) {
                int col = cb + n * 16 + lr;
                int idx = col * 64 + (((kk * 4 + lg) ^ (lr & 7)) << 3);
                bh[n] = *(const short8*)&sB[0][idx];
                bl[n] = *(const short8*)&sB[1][idx];
            }
            #pragma unroll
            for (int m = 0; m < 4; ++m)
                #pragma unroll
                for (int n = 0; n < 2; ++n) {
                    acc[m][n] = __builtin_amdgcn_mfma_f32_16x16x32_bf16(ah[m], bh[n], acc[m][n], 0, 0, 0);
                    acc[m][n] = __builtin_amdgcn_mfma_f32_16x16x32_bf16(ah[m], bl[n], acc[m][n], 0, 0, 0);
                    acc[m][n] = __builtin_amdgcn_mfma_f32_16x16x32_bf16(al[m], bh[n], acc[m][n], 0, 0, 0);
                }
        }
        __syncthreads();
    }

    // epilogue: C/D frag mapping col=lane&15, row=(lane>>4)*4+reg
    #pragma unroll
    for (int m = 0; m < 4; ++m) {
        int grow = row0 + rb + m * 16 + lg * 4;
        #pragma unroll
        for (int n = 0; n < 2; ++n) {
            int gcol = col0 + cb + n * 16 + lr;
            float bv = bias ? bias[gcol] : 0.f;
            #pragma unroll
            for (int q = 0; q < 4; ++q) {
                int r = grow + q;
                if (r >= M) continue;
                float v = acc[m][n][q] + bv;
                if (act == 1)      v = v > 0.f ? v : expm1f(v);
                else if (act == 2) v = 1.f / (1.f + expf(-v));
                size_t o = (size_t)r * N + gcol;
                if (Cf) Cf[o] = v;
                else { u16 h, l; bf16split(v, h, l); Ch[o] = h; Cl[o] = l; }
            }
        }
    }
}

// ---------------------------------------------------------------------------
// weight prep: W[K,N] fp32 -> transposed hi/lo bf16 planes [N,K]
// ---------------------------------------------------------------------------
__global__ __launch_bounds__(256)
void wsplit_kernel(const float* __restrict__ W, u16* __restrict__ Th,
                   u16* __restrict__ Tl, int K, int N)
{
    int n = blockIdx.x * 256 + threadIdx.x;
    int k = blockIdx.y;
    if (n >= N) return;
    u16 h, l;
    bf16split(W[(size_t)k * N + n], h, l);
    Th[(size_t)n * K + k] = h;
    Tl[(size_t)n * K + k] = l;
}

__global__ __launch_bounds__(256)
void xsplit_kernel(const float* __restrict__ x, u16* __restrict__ xh,
                   u16* __restrict__ xl, int total)
{
    int i = blockIdx.x * 256 + threadIdx.x;
    if (i >= total) return;
    u16 h, l;
    bf16split(x[i], h, l);
    xh[i] = h; xl[i] = l;
}

// ---------------------------------------------------------------------------
// CSR build: histogram -> exclusive scan -> scatter (dst-bucketed src lists)
// ---------------------------------------------------------------------------
__global__ __launch_bounds__(256)
void histo_kernel(const int* __restrict__ ei, int E, int Etot, int* __restrict__ deg)
{
    int e = blockIdx.x * 256 + threadIdx.x;
    if (e >= Etot) return;
    int dst = (e < E) ? ei[E + e] : (e - E);
    atomicAdd(&deg[dst], 1);
}

__global__ __launch_bounds__(256)
void scan1_kernel(const int* __restrict__ deg, int* __restrict__ off,
                  int* __restrict__ bsum, int N)
{
    __shared__ int sh[256];
    int base = blockIdx.x * 1024;
    int t = threadIdx.x;
    int v[4]; int s = 0;
    #pragma unroll
    for (int i = 0; i < 4; ++i) {
        int idx = base + t * 4 + i;
        v[i] = (idx < N) ? deg[idx] : 0;
        s += v[i];
    }
    sh[t] = s;
    __syncthreads();
    for (int d = 1; d < 256; d <<= 1) {
        int x = 0;
        if (t >= d) x = sh[t - d];
        __syncthreads();
        if (t >= d) sh[t] += x;
        __syncthreads();
    }
    int excl = (t > 0) ? sh[t - 1] : 0;
    #pragma unroll
    for (int i = 0; i < 4; ++i) {
        int idx = base + t * 4 + i;
        if (idx < N) off[idx] = excl;
        excl += v[i];
    }
    if (t == 255) bsum[blockIdx.x] = sh[255];
}

__global__ void scan2_kernel(int* __restrict__ bsum, int nb, int* __restrict__ off_last)
{
    if (threadIdx.x == 0) {
        int run = 0;
        for (int i = 0; i < nb; ++i) { int v = bsum[i]; bsum[i] = run; run += v; }
        *off_last = run;
    }
}

__global__ __launch_bounds__(256)
void scan3_kernel(int* __restrict__ off, const int* __restrict__ bsum, int N)
{
    int i = blockIdx.x * 256 + threadIdx.x;
    if (i < N) off[i] += bsum[i >> 10];
}

__global__ __launch_bounds__(256)
void scatter_kernel(const int* __restrict__ ei, int E, int Etot,
                    const int* __restrict__ off, int* __restrict__ cnt,
                    int* __restrict__ csrc)
{
    int e = blockIdx.x * 256 + threadIdx.x;
    if (e >= Etot) return;
    int src, dst;
    if (e < E) { src = ei[e]; dst = ei[E + e]; }
    else       { src = dst = e - E; }
    int pos = off[dst] + atomicAdd(&cnt[dst], 1);
    csrc[pos] = src;
}

// ---------------------------------------------------------------------------
// Fused GATv2 edge pass: one wave per destination node; writes hi/lo bf16.
// ---------------------------------------------------------------------------
__global__ __launch_bounds__(256)
void gat_fused(const float* __restrict__ xl, const float* __restrict__ xr,
               const int* __restrict__ off, const int* __restrict__ csrc,
               const float* __restrict__ att, const float* __restrict__ bias,
               u16* __restrict__ oh, u16* __restrict__ ol, int N)
{
    const int wave = threadIdx.x >> 6;
    const int lane = threadIdx.x & 63;
    const int node = blockIdx.x * 4 + wave;
    if (node >= N) return;

    const float a0 = att[lane];
    const float a1 = att[lane + 64];
    const float xr0 = xr[(size_t)node * 128 + lane];
    const float xr1 = xr[(size_t)node * 128 + lane + 64];

    float acc0 = 0.f, acc1 = 0.f, s0 = 0.f, s1 = 0.f;
    const int beg = off[node];
    const int end = off[node + 1];

    for (int e = beg; e < end; ++e) {
        int src = csrc[e];
        const float* px = xl + (size_t)src * 128;
        float x0 = px[lane];
        float x1 = px[lane + 64];
        float z0 = x0 + xr0; z0 = z0 > 0.f ? z0 : 0.2f * z0; z0 *= a0;
        float z1 = x1 + xr1; z1 = z1 > 0.f ? z1 : 0.2f * z1; z1 *= a1;
        #pragma unroll
        for (int m = 1; m < 32; m <<= 1) {
            z0 += __shfl_xor(z0, m, 64);
            z1 += __shfl_xor(z1, m, 64);
        }
        float p0 = __expf(z0);
        float p1 = __expf(z1);
        s0 += p0; s1 += p1;
        acc0 = fmaf(p0, x0, acc0);
        acc1 = fmaf(p1, x1, acc1);
    }

    float v0 = acc0 / s0 + bias[lane];
    float v1 = acc1 / s1 + bias[lane + 64];
    v0 = v0 > 0.f ? v0 : expm1f(v0);
    v1 = v1 > 0.f ? v1 : expm1f(v1);
    u16 h, l;
    bf16split(v0, h, l);
    oh[(size_t)node * 128 + lane] = h;
    ol[(size_t)node * 128 + lane] = l;
    bf16split(v1, h, l);
    oh[(size_t)node * 128 + lane + 64] = h;
    ol[(size_t)node * 128 + lane + 64] = l;
}

// ---------------------------------------------------------------------------
extern "C" void kernel_launch(void* const* d_in, const int* in_sizes, int n_in,
                              void* d_out, int out_size, void* d_ws, size_t ws_size,
                              hipStream_t stream)
{
    const float* x    = (const float*)d_in[0];
    const int*   ei   = (const int*)  d_in[1];
    const float* Wl1  = (const float*)d_in[2];
    const float* Wr1  = (const float*)d_in[3];
    const float* att1 = (const float*)d_in[4];
    const float* b1   = (const float*)d_in[5];
    const float* Wl2  = (const float*)d_in[6];
    const float* Wr2  = (const float*)d_in[7];
    const float* att2 = (const float*)d_in[8];
    const float* b2   = (const float*)d_in[9];
    const float* W1   = (const float*)d_in[10];
    const float* bb1  = (const float*)d_in[11];
    const float* W2   = (const float*)d_in[12];
    const float* bb2  = (const float*)d_in[13];
    const float* W3   = (const float*)d_in[14];
    const float* bb3  = (const float*)d_in[15];
    float* out = (float*)d_out;

    const int Nn   = in_sizes[0] / 128;   // nodes
    const int E    = in_sizes[1] / 2;
    const int Etot = E + Nn;

    // ---- workspace layout (256B-aligned slabs) ----
    char* base = (char*)d_ws;
    size_t woff = 0;
    auto alloc = [&](size_t bytes) -> void* {
        woff = (woff + 255) & ~(size_t)255;
        void* p = base + woff;
        woff += bytes;
        return p;
    };
    float* xlbuf = (float*)alloc((size_t)Nn * 128 * 4);   // overlaid by t1 planes in MLP
    float* xrbuf = (float*)alloc((size_t)Nn * 128 * 4);   // overlaid by t2 planes in MLP
    u16* xh  = (u16*)alloc((size_t)Nn * 128 * 2);
    u16* xlo = (u16*)alloc((size_t)Nn * 128 * 2);
    u16* h1h = (u16*)alloc((size_t)Nn * 128 * 2);
    u16* h1l = (u16*)alloc((size_t)Nn * 128 * 2);
    u16* h2h = (u16*)alloc((size_t)Nn * 128 * 2);
    u16* h2l = (u16*)alloc((size_t)Nn * 128 * 2);
    // transposed hi/lo weights
    auto wal = [&](int k, int n, u16*& th, u16*& tl) {
        th = (u16*)alloc((size_t)k * n * 2);
        tl = (u16*)alloc((size_t)k * n * 2);
    };
    u16 *WL1h, *WL1l, *WR1h, *WR1l, *WL2h, *WL2l, *WR2h, *WR2l;
    u16 *W1h, *W1l, *W2h, *W2l, *W3h, *W3l;
    wal(128, 128, WL1h, WL1l); wal(128, 128, WR1h, WR1l);
    wal(128, 128, WL2h, WL2l); wal(128, 128, WR2h, WR2l);
    wal(128, 640, W1h, W1l);   wal(640, 320, W2h, W2l);   wal(320, 64, W3h, W3l);
    int* off  = (int*)alloc((size_t)(Nn + 1) * 4);
    int* bsum = (int*)alloc(64 * 4);
    int* deg  = (int*)alloc((size_t)Nn * 4);
    int* csrc = (int*)alloc((size_t)Etot * 4);

    dim3 blk(256);
    auto gemm = [&](const u16* Ah, const u16* Al, const u16* Bh, const u16* Bl,
                    const float* bias, float* Cf, u16* Ch, u16* Cl,
                    int M, int N, int K, int act) {
        dim3 grid(N / BN, (M + BM - 1) / BM);
        hipLaunchKernelGGL(gemm_mfma, grid, blk, 0, stream,
                           Ah, Al, Bh, Bl, bias, Cf, Ch, Cl, M, N, K, act);
    };
    auto wsplit = [&](const float* W, int K, int N, u16* Th, u16* Tl) {
        dim3 grid((N + 255) / 256, K);
        hipLaunchKernelGGL(wsplit_kernel, grid, blk, 0, stream, W, Th, Tl, K, N);
    };

    const int eb  = (Etot + 255) / 256;
    const int nb  = (Nn + 1023) / 1024;
    const int nb2 = (Nn + 255) / 256;
    const int gatb = (Nn + 3) / 4;

    // ---- build CSR (once) ----
    hipMemsetAsync(deg, 0, (size_t)Nn * sizeof(int), stream);
    hipLaunchKernelGGL(histo_kernel, dim3(eb), blk, 0, stream, ei, E, Etot, deg);
    hipLaunchKernelGGL(scan1_kernel, dim3(nb), blk, 0, stream, deg, off, bsum, Nn);
    hipLaunchKernelGGL(scan2_kernel, dim3(1), dim3(64), 0, stream, bsum, nb, off + Nn);
    hipLaunchKernelGGL(scan3_kernel, dim3(nb2), blk, 0, stream, off, bsum, Nn);
    hipMemsetAsync(deg, 0, (size_t)Nn * sizeof(int), stream);
    hipLaunchKernelGGL(scatter_kernel, dim3(eb), blk, 0, stream, ei, E, Etot, off, deg, csrc);

    // ---- input/weight splits ----
    hipLaunchKernelGGL(xsplit_kernel, dim3((Nn * 128 + 255) / 256), blk, 0, stream,
                       x, xh, xlo, Nn * 128);
    wsplit(Wl1, 128, 128, WL1h, WL1l);
    wsplit(Wr1, 128, 128, WR1h, WR1l);
    wsplit(Wl2, 128, 128, WL2h, WL2l);
    wsplit(Wr2, 128, 128, WR2h, WR2l);
    wsplit(W1, 128, 640, W1h, W1l);
    wsplit(W2, 640, 320, W2h, W2l);
    wsplit(W3, 320, 64, W3h, W3l);

    // ---- conv1 ----
    gemm(xh, xlo, WL1h, WL1l, nullptr, xlbuf, nullptr, nullptr, Nn, 128, 128, 0);
    gemm(xh, xlo, WR1h, WR1l, nullptr, xrbuf, nullptr, nullptr, Nn, 128, 128, 0);
    hipLaunchKernelGGL(gat_fused, dim3(gatb), blk, 0, stream,
                       xlbuf, xrbuf, off, csrc, att1, b1, h1h, h1l, Nn);

    // ---- conv2 ----
    gemm(h1h, h1l, WL2h, WL2l, nullptr, xlbuf, nullptr, nullptr, Nn, 128, 128, 0);
    gemm(h1h, h1l, WR2h, WR2l, nullptr, xrbuf, nullptr, nullptr, Nn, 128, 128, 0);
    hipLaunchKernelGGL(gat_fused, dim3(gatb), blk, 0, stream,
                       xlbuf, xrbuf, off, csrc, att2, b2, h2h, h2l, Nn);

    // ---- MLP head (chunked; t1/t2 planes overlay dead xlbuf/xrbuf) ----
    const int CHUNK = 8192;
    u16* t1h = (u16*)xlbuf;
    u16* t1l = t1h + (size_t)CHUNK * 640;
    u16* t2h = (u16*)xrbuf;
    u16* t2l = t2h + (size_t)CHUNK * 320;
    for (int c0 = 0; c0 < Nn; c0 += CHUNK) {
        int cm = (Nn - c0) < CHUNK ? (Nn - c0) : CHUNK;
        gemm(h2h + (size_t)c0 * 128, h2l + (size_t)c0 * 128, W1h, W1l, bb1,
             nullptr, t1h, t1l, cm, 640, 128, 1);
        gemm(t1h, t1l, W2h, W2l, bb2, nullptr, t2h, t2l, cm, 320, 640, 1);
        gemm(t2h, t2l, W3h, W3l, bb3, out + (size_t)c0 * 64, nullptr, nullptr, cm, 64, 320, 2);
    }
}

// Round 4
// 802.334 us; speedup vs baseline: 2.4965x; 1.2527x over previous
//
#include <hip/hip_runtime.h>
#include <cstdint>
#include <cstddef>

typedef __attribute__((ext_vector_type(8))) short short8;
typedef __attribute__((ext_vector_type(4))) float f32x4;
typedef unsigned short u16;
typedef unsigned int u32;

__device__ __forceinline__ u16 bf16rne(float v)
{
    union { float f; u32 u; } a; a.f = v;
    return (u16)((a.u + 0x7fffu + ((a.u >> 16) & 1u)) >> 16);
}

// round-to-nearest-even bf16 split: v ~= hi + lo
__device__ __forceinline__ void bf16split(float v, u16& h, u16& l)
{
    union { float f; u32 u; } a; a.f = v;
    u32 r = (a.u + 0x7fffu + ((a.u >> 16) & 1u)) & 0xffff0000u;
    h = (u16)(r >> 16);
    union { u32 u; float f; } b; b.u = r;
    l = bf16rne(v - b.f);
}

__device__ __forceinline__ float bf16f(u16 h)
{
    union { u32 u; float f; } b; b.u = ((u32)h) << 16;
    return b.f;
}

// ---------------------------------------------------------------------------
// Split-bf16 MFMA GEMM: C = act(A @ Bt^T + bias). A[M,K] hi/lo bf16 planes,
// Bt[N,K] hi/lo bf16 planes (weights pre-transposed).
// Out modes: Cf!=0 -> fp32; else Cl!=0 -> hi/lo bf16 planes; else packed bf16.
// act: 0=none 1=ELU 2=sigmoid. Tile BM=128,BN=64,BK=64; 4 waves.
// ---------------------------------------------------------------------------
#define BM 128
#define BN 64
#define BK 64

__global__ __launch_bounds__(256)
void gemm_mfma(const u16* __restrict__ Ah, const u16* __restrict__ Al,
               const u16* __restrict__ Bh, const u16* __restrict__ Bl,
               const float* __restrict__ bias,
               float* __restrict__ Cf, u16* __restrict__ Ch, u16* __restrict__ Cl,
               int M, int N, int K, int act)
{
    __shared__ __align__(16) u16 sA[2][BM * BK];
    __shared__ __align__(16) u16 sB[2][BN * BK];
    const int t = threadIdx.x;
    const int w = t >> 6, lane = t & 63;
    const int lr = lane & 15, lg = lane >> 4;
    const int row0 = blockIdx.y * BM, col0 = blockIdx.x * BN;
    const int rb = (w & 1) * 64, cb = (w >> 1) * 32;

    f32x4 acc[4][2];
    #pragma unroll
    for (int m = 0; m < 4; ++m)
        #pragma unroll
        for (int n = 0; n < 2; ++n) acc[m][n] = (f32x4)0.f;

    for (int k0 = 0; k0 < K; k0 += BK) {
        #pragma unroll
        for (int i = 0; i < 4; ++i) {
            int id = t + 256 * i;
            int row = id >> 3, kc = id & 7;
            int grow = row0 + row;
            uint4 vh = make_uint4(0, 0, 0, 0), vl = vh;
            if (grow < M) {
                size_t g = (size_t)grow * K + k0 + kc * 8;
                vh = *(const uint4*)(Ah + g);
                vl = *(const uint4*)(Al + g);
            }
            int idx = row * 64 + ((kc ^ (row & 7)) << 3);
            *(uint4*)&sA[0][idx] = vh;
            *(uint4*)&sA[1][idx] = vl;
        }
        #pragma unroll
        for (int i = 0; i < 2; ++i) {
            int id = t + 256 * i;
            int col = id >> 3, kc = id & 7;
            size_t g = (size_t)(col0 + col) * K + k0 + kc * 8;
            uint4 vh = *(const uint4*)(Bh + g);
            uint4 vl = *(const uint4*)(Bl + g);
            int idx = col * 64 + ((kc ^ (col & 7)) << 3);
            *(uint4*)&sB[0][idx] = vh;
            *(uint4*)&sB[1][idx] = vl;
        }
        __syncthreads();
        #pragma unroll
        for (int kk = 0; kk < 2; ++kk) {
            short8 ah[4], al[4], bh[2], bl[2];
            #pragma unroll
            for (int m = 0; m < 4; ++m) {
                int row = rb + m * 16 + lr;
                int idx = row * 64 + (((kk * 4 + lg) ^ (lr & 7)) << 3);
                ah[m] = *(const short8*)&sA[0][idx];
                al[m] = *(const short8*)&sA[1][idx];
            }
            #pragma unroll
            for (int n = 0; n < 2; ++n) {
                int col = cb + n * 16 + lr;
                int idx = col * 64 + (((kk * 4 + lg) ^ (lr & 7)) << 3);
                bh[n] = *(const short8*)&sB[0][idx];
                bl[n] = *(const short8*)&sB[1][idx];
            }
            #pragma unroll
            for (int m = 0; m < 4; ++m)
                #pragma unroll
                for (int n = 0; n < 2; ++n) {
                    acc[m][n] = __builtin_amdgcn_mfma_f32_16x16x32_bf16(ah[m], bh[n], acc[m][n], 0, 0, 0);
                    acc[m][n] = __builtin_amdgcn_mfma_f32_16x16x32_bf16(ah[m], bl[n], acc[m][n], 0, 0, 0);
                    acc[m][n] = __builtin_amdgcn_mfma_f32_16x16x32_bf16(al[m], bh[n], acc[m][n], 0, 0, 0);
                }
        }
        __syncthreads();
    }

    #pragma unroll
    for (int m = 0; m < 4; ++m) {
        int grow = row0 + rb + m * 16 + lg * 4;
        #pragma unroll
        for (int n = 0; n < 2; ++n) {
            int gcol = col0 + cb + n * 16 + lr;
            float bv = bias ? bias[gcol] : 0.f;
            #pragma unroll
            for (int q = 0; q < 4; ++q) {
                int r = grow + q;
                if (r >= M) continue;
                float v = acc[m][n][q] + bv;
                if (act == 1)      v = v > 0.f ? v : expm1f(v);
                else if (act == 2) v = 1.f / (1.f + expf(-v));
                size_t o = (size_t)r * N + gcol;
                if (Cf) Cf[o] = v;
                else if (Cl) { u16 h, l; bf16split(v, h, l); Ch[o] = h; Cl[o] = l; }
                else Ch[o] = bf16rne(v);
            }
        }
    }
}

// ---------------------------------------------------------------------------
// weight prep
// ---------------------------------------------------------------------------
// conv weights: Wl,Wr [128,128] -> Bt [256,128] hi/lo (rows 0-127 Wl, 128-255 Wr)
__global__ __launch_bounds__(256)
void wsplit_conv(const float* __restrict__ Wl1, const float* __restrict__ Wr1,
                 const float* __restrict__ Wl2, const float* __restrict__ Wr2,
                 u16* __restrict__ T1h, u16* __restrict__ T1l,
                 u16* __restrict__ T2h, u16* __restrict__ T2l)
{
    int idx = blockIdx.x * 256 + threadIdx.x;   // 0..16383
    int z = blockIdx.y;                          // 0..3
    int k = idx >> 7, n = idx & 127;
    const float* W = (z == 0) ? Wl1 : (z == 1) ? Wr1 : (z == 2) ? Wl2 : Wr2;
    u16* Th = (z < 2) ? T1h : T2h;
    u16* Tl = (z < 2) ? T1l : T2l;
    int half = z & 1;
    u16 h, l;
    bf16split(W[(size_t)k * 128 + n], h, l);
    size_t o = (size_t)(n + half * 128) * 128 + k;
    Th[o] = h; Tl[o] = l;
}

__global__ __launch_bounds__(256)
void wsplit_kernel(const float* __restrict__ W, u16* __restrict__ Th,
                   u16* __restrict__ Tl, int K, int N)
{
    int n = blockIdx.x * 256 + threadIdx.x;
    int k = blockIdx.y;
    if (n >= N) return;
    u16 h, l;
    bf16split(W[(size_t)k * N + n], h, l);
    Th[(size_t)n * K + k] = h;
    Tl[(size_t)n * K + k] = l;
}

__global__ __launch_bounds__(256)
void xsplit_kernel(const float* __restrict__ x, u16* __restrict__ xh,
                   u16* __restrict__ xl, int total)
{
    int i = blockIdx.x * 256 + threadIdx.x;
    if (i >= total) return;
    u16 h, l;
    bf16split(x[i], h, l);
    xh[i] = h; xl[i] = l;
}

// ---------------------------------------------------------------------------
// CSR build
// ---------------------------------------------------------------------------
__global__ __launch_bounds__(256)
void histo_kernel(const int* __restrict__ ei, int E, int Etot, int* __restrict__ deg)
{
    int e = blockIdx.x * 256 + threadIdx.x;
    if (e >= Etot) return;
    int dst = (e < E) ? ei[E + e] : (e - E);
    atomicAdd(&deg[dst], 1);
}

__global__ __launch_bounds__(256)
void scan1_kernel(const int* __restrict__ deg, int* __restrict__ off,
                  int* __restrict__ bsum, int N)
{
    __shared__ int sh[256];
    int base = blockIdx.x * 1024;
    int t = threadIdx.x;
    int v[4]; int s = 0;
    #pragma unroll
    for (int i = 0; i < 4; ++i) {
        int idx = base + t * 4 + i;
        v[i] = (idx < N) ? deg[idx] : 0;
        s += v[i];
    }
    sh[t] = s;
    __syncthreads();
    for (int d = 1; d < 256; d <<= 1) {
        int x = 0;
        if (t >= d) x = sh[t - d];
        __syncthreads();
        if (t >= d) sh[t] += x;
        __syncthreads();
    }
    int excl = (t > 0) ? sh[t - 1] : 0;
    #pragma unroll
    for (int i = 0; i < 4; ++i) {
        int idx = base + t * 4 + i;
        if (idx < N) off[idx] = excl;
        excl += v[i];
    }
    if (t == 255) bsum[blockIdx.x] = sh[255];
}

__global__ void scan2_kernel(int* __restrict__ bsum, int nb, int* __restrict__ off_last)
{
    if (threadIdx.x == 0) {
        int run = 0;
        for (int i = 0; i < nb; ++i) { int v = bsum[i]; bsum[i] = run; run += v; }
        *off_last = run;
    }
}

__global__ __launch_bounds__(256)
void scan3_kernel(int* __restrict__ off, const int* __restrict__ bsum, int N)
{
    int i = blockIdx.x * 256 + threadIdx.x;
    if (i < N) off[i] += bsum[i >> 10];
}

__global__ __launch_bounds__(256)
void scatter_kernel(const int* __restrict__ ei, int E, int Etot,
                    const int* __restrict__ off, int* __restrict__ cnt,
                    int* __restrict__ csrc)
{
    int e = blockIdx.x * 256 + threadIdx.x;
    if (e >= Etot) return;
    int src, dst;
    if (e < E) { src = ei[e]; dst = ei[E + e]; }
    else       { src = dst = e - E; }
    int pos = off[dst] + atomicAdd(&cnt[dst], 1);
    csrc[pos] = src;
}

// ---------------------------------------------------------------------------
// Fused GATv2 edge pass. xlxr: [node][256] packed bf16 (cols 0-127 = xl,
// 128-255 = xr). One wave per dst node; lane l owns channels 2l, 2l+1
// (head = l>>4 -> 16-lane groups). Per edge: one u32 gather, 4-shuffle
// logit reduce, online weighted accumulation. Output: hi/lo bf16 planes.
// ---------------------------------------------------------------------------
__global__ __launch_bounds__(256)
void gat_fused(const u16* __restrict__ xlxr,
               const int* __restrict__ off, const int* __restrict__ csrc,
               const float* __restrict__ att, const float* __restrict__ bias,
               u16* __restrict__ oh, u16* __restrict__ ol, int N)
{
    const int wave = threadIdx.x >> 6;
    const int lane = threadIdx.x & 63;
    const int node = blockIdx.x * 4 + wave;
    if (node >= N) return;
    const int c = lane * 2;

    const float a0 = att[c];
    const float a1 = att[c + 1];
    u32 xrw = *(const u32*)(xlxr + (size_t)node * 256 + 128 + c);
    const float xr0 = bf16f((u16)xrw);
    const float xr1 = bf16f((u16)(xrw >> 16));

    float acc0 = 0.f, acc1 = 0.f, s = 0.f;
    const int beg = off[node];
    const int end = off[node + 1];

    for (int e = beg; e < end; ++e) {
        int src = csrc[e];
        u32 xw = *(const u32*)(xlxr + (size_t)src * 256 + c);
        float x0 = bf16f((u16)xw);
        float x1 = bf16f((u16)(xw >> 16));
        float z0 = x0 + xr0; z0 = z0 > 0.f ? z0 : 0.2f * z0;
        float z1 = x1 + xr1; z1 = z1 > 0.f ? z1 : 0.2f * z1;
        float z = fmaf(z0, a0, z1 * a1);
        #pragma unroll
        for (int m = 1; m < 16; m <<= 1)
            z += __shfl_xor(z, m, 64);
        float p = __expf(z);
        s += p;
        acc0 = fmaf(p, x0, acc0);
        acc1 = fmaf(p, x1, acc1);
    }

    float inv = 1.f / s;
    float v0 = acc0 * inv + bias[c];
    float v1 = acc1 * inv + bias[c + 1];
    v0 = v0 > 0.f ? v0 : expm1f(v0);
    v1 = v1 > 0.f ? v1 : expm1f(v1);
    u16 h0, l0, h1, l1;
    bf16split(v0, h0, l0);
    bf16split(v1, h1, l1);
    size_t o = (size_t)node * 128 + c;
    *(u32*)(oh + o) = (u32)h0 | ((u32)h1 << 16);
    *(u32*)(ol + o) = (u32)l0 | ((u32)l1 << 16);
}

// ---------------------------------------------------------------------------
extern "C" void kernel_launch(void* const* d_in, const int* in_sizes, int n_in,
                              void* d_out, int out_size, void* d_ws, size_t ws_size,
                              hipStream_t stream)
{
    const float* x    = (const float*)d_in[0];
    const int*   ei   = (const int*)  d_in[1];
    const float* Wl1  = (const float*)d_in[2];
    const float* Wr1  = (const float*)d_in[3];
    const float* att1 = (const float*)d_in[4];
    const float* b1   = (const float*)d_in[5];
    const float* Wl2  = (const float*)d_in[6];
    const float* Wr2  = (const float*)d_in[7];
    const float* att2 = (const float*)d_in[8];
    const float* b2   = (const float*)d_in[9];
    const float* W1   = (const float*)d_in[10];
    const float* bb1  = (const float*)d_in[11];
    const float* W2   = (const float*)d_in[12];
    const float* bb2  = (const float*)d_in[13];
    const float* W3   = (const float*)d_in[14];
    const float* bb3  = (const float*)d_in[15];
    float* out = (float*)d_out;

    const int Nn   = in_sizes[0] / 128;
    const int E    = in_sizes[1] / 2;
    const int Etot = E + Nn;

    // ---- workspace layout. Front region (xh,xlo,xlxr,h1h,h1l = 76.8 MB) is
    // dead by MLP time and is overlaid by t1/t2 (CHUNK=19968 -> 76.7 MB). ----
    char* base = (char*)d_ws;
    size_t woff = 0;
    auto alloc = [&](size_t bytes) -> void* {
        woff = (woff + 255) & ~(size_t)255;
        void* p = base + woff;
        woff += bytes;
        return p;
    };
    u16* xh   = (u16*)alloc((size_t)Nn * 128 * 2);
    u16* xlo  = (u16*)alloc((size_t)Nn * 128 * 2);
    u16* xlxr = (u16*)alloc((size_t)Nn * 256 * 2);
    u16* h1h  = (u16*)alloc((size_t)Nn * 128 * 2);
    u16* h1l  = (u16*)alloc((size_t)Nn * 128 * 2);
    u16* h2h  = (u16*)alloc((size_t)Nn * 128 * 2);
    u16* h2l  = (u16*)alloc((size_t)Nn * 128 * 2);
    auto wal = [&](int k, int n, u16*& th, u16*& tl) {
        th = (u16*)alloc((size_t)k * n * 2);
        tl = (u16*)alloc((size_t)k * n * 2);
    };
    u16 *WLR1h, *WLR1l, *WLR2h, *WLR2l, *W1h, *W1l, *W2h, *W2l, *W3h, *W3l;
    wal(256, 128, WLR1h, WLR1l);
    wal(256, 128, WLR2h, WLR2l);
    wal(128, 640, W1h, W1l);
    wal(640, 320, W2h, W2l);
    wal(320, 64, W3h, W3l);
    int* off  = (int*)alloc((size_t)(Nn + 1) * 4);
    int* bsum = (int*)alloc(64 * 4);
    int* deg  = (int*)alloc((size_t)Nn * 4);
    int* csrc = (int*)alloc((size_t)Etot * 4);

    dim3 blk(256);
    auto gemm = [&](const u16* Ah, const u16* Al, const u16* Bh, const u16* Bl,
                    const float* bias, float* Cf, u16* Ch, u16* Cl,
                    int M, int N, int K, int act) {
        dim3 grid(N / BN, (M + BM - 1) / BM);
        hipLaunchKernelGGL(gemm_mfma, grid, blk, 0, stream,
                           Ah, Al, Bh, Bl, bias, Cf, Ch, Cl, M, N, K, act);
    };

    const int eb  = (Etot + 255) / 256;
    const int nb  = (Nn + 1023) / 1024;
    const int nb2 = (Nn + 255) / 256;
    const int gatb = (Nn + 3) / 4;

    // ---- CSR build (once) ----
    hipMemsetAsync(deg, 0, (size_t)Nn * sizeof(int), stream);
    hipLaunchKernelGGL(histo_kernel, dim3(eb), blk, 0, stream, ei, E, Etot, deg);
    hipLaunchKernelGGL(scan1_kernel, dim3(nb), blk, 0, stream, deg, off, bsum, Nn);
    hipLaunchKernelGGL(scan2_kernel, dim3(1), dim3(64), 0, stream, bsum, nb, off + Nn);
    hipLaunchKernelGGL(scan3_kernel, dim3(nb2), blk, 0, stream, off, bsum, Nn);
    hipMemsetAsync(deg, 0, (size_t)Nn * sizeof(int), stream);
    hipLaunchKernelGGL(scatter_kernel, dim3(eb), blk, 0, stream, ei, E, Etot, off, deg, csrc);

    // ---- splits ----
    hipLaunchKernelGGL(xsplit_kernel, dim3((Nn * 128 + 255) / 256), blk, 0, stream,
                       x, xh, xlo, Nn * 128);
    hipLaunchKernelGGL(wsplit_conv, dim3(64, 4), blk, 0, stream,
                       Wl1, Wr1, Wl2, Wr2, WLR1h, WLR1l, WLR2h, WLR2l);
    hipLaunchKernelGGL(wsplit_kernel, dim3((640 + 255) / 256, 128), blk, 0, stream, W1, W1h, W1l, 128, 640);
    hipLaunchKernelGGL(wsplit_kernel, dim3((320 + 255) / 256, 640), blk, 0, stream, W2, W2h, W2l, 640, 320);
    hipLaunchKernelGGL(wsplit_kernel, dim3((64 + 255) / 256, 320), blk, 0, stream, W3, W3h, W3l, 320, 64);

    // ---- conv1 ----
    gemm(xh, xlo, WLR1h, WLR1l, nullptr, nullptr, xlxr, nullptr, Nn, 256, 128, 0);
    hipLaunchKernelGGL(gat_fused, dim3(gatb), blk, 0, stream,
                       xlxr, off, csrc, att1, b1, h1h, h1l, Nn);

    // ---- conv2 ----
    gemm(h1h, h1l, WLR2h, WLR2l, nullptr, nullptr, xlxr, nullptr, Nn, 256, 128, 0);
    hipLaunchKernelGGL(gat_fused, dim3(gatb), blk, 0, stream,
                       xlxr, off, csrc, att2, b2, h2h, h2l, Nn);

    // ---- MLP head (t1/t2 overlay the dead 76.8 MB front region) ----
    const int CHUNK = 19968;   // 3840 B/row * 19968 = 76.7 MB <= 76.8 MB front
    u16* t1h = (u16*)base;
    u16* t1l = t1h + (size_t)CHUNK * 640;
    u16* t2h = t1l + (size_t)CHUNK * 640;
    u16* t2l = t2h + (size_t)CHUNK * 320;
    for (int c0 = 0; c0 < Nn; c0 += CHUNK) {
        int cm = (Nn - c0) < CHUNK ? (Nn - c0) : CHUNK;
        gemm(h2h + (size_t)c0 * 128, h2l + (size_t)c0 * 128, W1h, W1l, bb1,
             nullptr, t1h, t1l, cm, 640, 128, 1);
        gemm(t1h, t1l, W2h, W2l, bb2, nullptr, t2h, t2l, cm, 320, 640, 1);
        gemm(t2h, t2l, W3h, W3l, bb3, out + (size_t)c0 * 64, nullptr, nullptr, cm, 64, 320, 2);
    }
}

// Round 5
// 457.778 us; speedup vs baseline: 4.3755x; 1.7527x over previous
//
#include <hip/hip_runtime.h>
#include <cstdint>
#include <cstddef>

typedef __attribute__((ext_vector_type(8))) short short8;
typedef __attribute__((ext_vector_type(4))) float f32x4;
typedef unsigned short u16;
typedef unsigned int u32;

__device__ __forceinline__ u16 bf16rne(float v)
{
    union { float f; u32 u; } a; a.f = v;
    return (u16)((a.u + 0x7fffu + ((a.u >> 16) & 1u)) >> 16);
}

__device__ __forceinline__ float bf16f(u16 h)
{
    union { u32 u; float f; } b; b.u = ((u32)h) << 16;
    return b.f;
}

// ---------------------------------------------------------------------------
// bf16 MFMA GEMM: C = act(A @ Bt^T + bias). A[M,K] bf16, Bt[N,K] bf16
// (weights pre-transposed). Out: Cf!=0 -> fp32, else packed bf16 Cp.
// act: 0=none 1=ELU 2=sigmoid. Tile BM=128,BN=64,BK=64; 4 waves;
// wave -> 64x32 via 4x2 16x16x32 MFMA frags. XOR-swizzled LDS.
// Requires N%64==0, K%64==0.
// ---------------------------------------------------------------------------
#define BM 128
#define BN 64
#define BK 64

__global__ __launch_bounds__(256)
void gemm_mfma(const u16* __restrict__ A, const u16* __restrict__ Bt,
               const float* __restrict__ bias,
               float* __restrict__ Cf, u16* __restrict__ Cp,
               int M, int N, int K, int act)
{
    __shared__ __align__(16) u16 sA[BM * BK];
    __shared__ __align__(16) u16 sB[BN * BK];
    const int t = threadIdx.x;
    const int w = t >> 6, lane = t & 63;
    const int lr = lane & 15, lg = lane >> 4;
    const int row0 = blockIdx.y * BM, col0 = blockIdx.x * BN;
    const int rb = (w & 1) * 64, cb = (w >> 1) * 32;

    f32x4 acc[4][2];
    #pragma unroll
    for (int m = 0; m < 4; ++m)
        #pragma unroll
        for (int n = 0; n < 2; ++n) acc[m][n] = (f32x4)0.f;

    for (int k0 = 0; k0 < K; k0 += BK) {
        // stage A: 128x64 bf16, 4 uint4 per thread
        #pragma unroll
        for (int i = 0; i < 4; ++i) {
            int id = t + 256 * i;
            int row = id >> 3, kc = id & 7;
            int grow = row0 + row;
            uint4 v = make_uint4(0, 0, 0, 0);
            if (grow < M)
                v = *(const uint4*)(A + (size_t)grow * K + k0 + kc * 8);
            *(uint4*)&sA[row * 64 + ((kc ^ (row & 7)) << 3)] = v;
        }
        // stage B: 64x64 bf16, 2 uint4 per thread
        #pragma unroll
        for (int i = 0; i < 2; ++i) {
            int id = t + 256 * i;
            int col = id >> 3, kc = id & 7;
            uint4 v = *(const uint4*)(Bt + (size_t)(col0 + col) * K + k0 + kc * 8);
            *(uint4*)&sB[col * 64 + ((kc ^ (col & 7)) << 3)] = v;
        }
        __syncthreads();
        #pragma unroll
        for (int kk = 0; kk < 2; ++kk) {
            short8 af[4], bf[2];
            #pragma unroll
            for (int m = 0; m < 4; ++m) {
                int row = rb + m * 16 + lr;
                af[m] = *(const short8*)&sA[row * 64 + (((kk * 4 + lg) ^ (lr & 7)) << 3)];
            }
            #pragma unroll
            for (int n = 0; n < 2; ++n) {
                int col = cb + n * 16 + lr;
                bf[n] = *(const short8*)&sB[col * 64 + (((kk * 4 + lg) ^ (lr & 7)) << 3)];
            }
            #pragma unroll
            for (int m = 0; m < 4; ++m)
                #pragma unroll
                for (int n = 0; n < 2; ++n)
                    acc[m][n] = __builtin_amdgcn_mfma_f32_16x16x32_bf16(af[m], bf[n], acc[m][n], 0, 0, 0);
        }
        __syncthreads();
    }

    // epilogue: C/D frag col=lane&15, row=(lane>>4)*4+reg
    #pragma unroll
    for (int m = 0; m < 4; ++m) {
        int grow = row0 + rb + m * 16 + lg * 4;
        #pragma unroll
        for (int n = 0; n < 2; ++n) {
            int gcol = col0 + cb + n * 16 + lr;
            float bv = bias ? bias[gcol] : 0.f;
            #pragma unroll
            for (int q = 0; q < 4; ++q) {
                int r = grow + q;
                if (r >= M) continue;
                float v = acc[m][n][q] + bv;
                if (act == 1)      v = v > 0.f ? v : expm1f(v);
                else if (act == 2) v = 1.f / (1.f + expf(-v));
                size_t o = (size_t)r * N + gcol;
                if (Cf) Cf[o] = v;
                else Cp[o] = bf16rne(v);
            }
        }
    }
}

// ---------------------------------------------------------------------------
// weight prep (fp32 [K,N] -> transposed bf16 [N,K])
// ---------------------------------------------------------------------------
__global__ __launch_bounds__(256)
void wsplit_conv(const float* __restrict__ Wl1, const float* __restrict__ Wr1,
                 const float* __restrict__ Wl2, const float* __restrict__ Wr2,
                 u16* __restrict__ T1, u16* __restrict__ T2)
{
    int idx = blockIdx.x * 256 + threadIdx.x;   // 0..16383
    int z = blockIdx.y;                          // 0..3
    int k = idx >> 7, n = idx & 127;
    const float* W = (z == 0) ? Wl1 : (z == 1) ? Wr1 : (z == 2) ? Wl2 : Wr2;
    u16* T = (z < 2) ? T1 : T2;
    int half = z & 1;
    T[(size_t)(n + half * 128) * 128 + k] = bf16rne(W[(size_t)k * 128 + n]);
}

__global__ __launch_bounds__(256)
void wsplit_kernel(const float* __restrict__ W, u16* __restrict__ T, int K, int N)
{
    int n = blockIdx.x * 256 + threadIdx.x;
    int k = blockIdx.y;
    if (n >= N) return;
    T[(size_t)n * K + k] = bf16rne(W[(size_t)k * N + n]);
}

__global__ __launch_bounds__(256)
void xsplit_kernel(const float* __restrict__ x, u16* __restrict__ xh, int total)
{
    int i = blockIdx.x * 256 + threadIdx.x;
    if (i >= total) return;
    xh[i] = bf16rne(x[i]);
}

// ---------------------------------------------------------------------------
// CSR build
// ---------------------------------------------------------------------------
__global__ __launch_bounds__(256)
void histo_kernel(const int* __restrict__ ei, int E, int Etot, int* __restrict__ deg)
{
    int e = blockIdx.x * 256 + threadIdx.x;
    if (e >= Etot) return;
    int dst = (e < E) ? ei[E + e] : (e - E);
    atomicAdd(&deg[dst], 1);
}

__global__ __launch_bounds__(256)
void scan1_kernel(const int* __restrict__ deg, int* __restrict__ off,
                  int* __restrict__ bsum, int N)
{
    __shared__ int sh[256];
    int base = blockIdx.x * 1024;
    int t = threadIdx.x;
    int v[4]; int s = 0;
    #pragma unroll
    for (int i = 0; i < 4; ++i) {
        int idx = base + t * 4 + i;
        v[i] = (idx < N) ? deg[idx] : 0;
        s += v[i];
    }
    sh[t] = s;
    __syncthreads();
    for (int d = 1; d < 256; d <<= 1) {
        int x = 0;
        if (t >= d) x = sh[t - d];
        __syncthreads();
        if (t >= d) sh[t] += x;
        __syncthreads();
    }
    int excl = (t > 0) ? sh[t - 1] : 0;
    #pragma unroll
    for (int i = 0; i < 4; ++i) {
        int idx = base + t * 4 + i;
        if (idx < N) off[idx] = excl;
        excl += v[i];
    }
    if (t == 255) bsum[blockIdx.x] = sh[255];
}

__global__ void scan2_kernel(int* __restrict__ bsum, int nb, int* __restrict__ off_last)
{
    if (threadIdx.x == 0) {
        int run = 0;
        for (int i = 0; i < nb; ++i) { int v = bsum[i]; bsum[i] = run; run += v; }
        *off_last = run;
    }
}

__global__ __launch_bounds__(256)
void scan3_kernel(int* __restrict__ off, const int* __restrict__ bsum, int N)
{
    int i = blockIdx.x * 256 + threadIdx.x;
    if (i < N) off[i] += bsum[i >> 10];
}

__global__ __launch_bounds__(256)
void scatter_kernel(const int* __restrict__ ei, int E, int Etot,
                    const int* __restrict__ off, int* __restrict__ cnt,
                    int* __restrict__ csrc)
{
    int e = blockIdx.x * 256 + threadIdx.x;
    if (e >= Etot) return;
    int src, dst;
    if (e < E) { src = ei[e]; dst = ei[E + e]; }
    else       { src = dst = e - E; }
    int pos = off[dst] + atomicAdd(&cnt[dst], 1);
    csrc[pos] = src;
}

// ---------------------------------------------------------------------------
// Fused GATv2 edge pass. xlxr [node][256] packed bf16 (0-127 xl, 128-255 xr).
// One wave per dst node; lane l owns channels 2l,2l+1; head = 16-lane group.
// Edge loop unrolled x4 with independent shuffle-reduce chains for ILP.
// Output: packed bf16 [node][128].
// ---------------------------------------------------------------------------
__global__ __launch_bounds__(256)
void gat_fused(const u16* __restrict__ xlxr,
               const int* __restrict__ off, const int* __restrict__ csrc,
               const float* __restrict__ att, const float* __restrict__ bias,
               u16* __restrict__ outp, int N)
{
    const int wave = threadIdx.x >> 6;
    const int lane = threadIdx.x & 63;
    const int node = blockIdx.x * 4 + wave;
    if (node >= N) return;
    const int c = lane * 2;

    const float a0 = att[c];
    const float a1 = att[c + 1];
    u32 xrw = *(const u32*)(xlxr + (size_t)node * 256 + 128 + c);
    const float xr0 = bf16f((u16)xrw);
    const float xr1 = bf16f((u16)(xrw >> 16));

    float acc0 = 0.f, acc1 = 0.f, s = 0.f;
    const int beg = off[node];
    const int end = off[node + 1];

    int e = beg;
    for (; e + 4 <= end; e += 4) {
        int s0 = csrc[e], s1 = csrc[e + 1], s2 = csrc[e + 2], s3 = csrc[e + 3];
        u32 wa = *(const u32*)(xlxr + (size_t)s0 * 256 + c);
        u32 wb = *(const u32*)(xlxr + (size_t)s1 * 256 + c);
        u32 wc = *(const u32*)(xlxr + (size_t)s2 * 256 + c);
        u32 wd = *(const u32*)(xlxr + (size_t)s3 * 256 + c);
        float xa0 = bf16f((u16)wa), xa1 = bf16f((u16)(wa >> 16));
        float xb0 = bf16f((u16)wb), xb1 = bf16f((u16)(wb >> 16));
        float xc0 = bf16f((u16)wc), xc1 = bf16f((u16)(wc >> 16));
        float xd0 = bf16f((u16)wd), xd1 = bf16f((u16)(wd >> 16));
        float t0, t1;
        t0 = xa0 + xr0; t0 = t0 > 0.f ? t0 : 0.2f * t0;
        t1 = xa1 + xr1; t1 = t1 > 0.f ? t1 : 0.2f * t1;
        float za = fmaf(t0, a0, t1 * a1);
        t0 = xb0 + xr0; t0 = t0 > 0.f ? t0 : 0.2f * t0;
        t1 = xb1 + xr1; t1 = t1 > 0.f ? t1 : 0.2f * t1;
        float zb = fmaf(t0, a0, t1 * a1);
        t0 = xc0 + xr0; t0 = t0 > 0.f ? t0 : 0.2f * t0;
        t1 = xc1 + xr1; t1 = t1 > 0.f ? t1 : 0.2f * t1;
        float zc = fmaf(t0, a0, t1 * a1);
        t0 = xd0 + xr0; t0 = t0 > 0.f ? t0 : 0.2f * t0;
        t1 = xd1 + xr1; t1 = t1 > 0.f ? t1 : 0.2f * t1;
        float zd = fmaf(t0, a0, t1 * a1);
        #pragma unroll
        for (int m = 1; m < 16; m <<= 1) {
            za += __shfl_xor(za, m, 64);
            zb += __shfl_xor(zb, m, 64);
            zc += __shfl_xor(zc, m, 64);
            zd += __shfl_xor(zd, m, 64);
        }
        float pa = __expf(za), pb = __expf(zb), pc = __expf(zc), pd = __expf(zd);
        s += (pa + pb) + (pc + pd);
        acc0 = fmaf(pa, xa0, fmaf(pb, xb0, fmaf(pc, xc0, fmaf(pd, xd0, acc0))));
        acc1 = fmaf(pa, xa1, fmaf(pb, xb1, fmaf(pc, xc1, fmaf(pd, xd1, acc1))));
    }
    for (; e < end; ++e) {
        int src = csrc[e];
        u32 xw = *(const u32*)(xlxr + (size_t)src * 256 + c);
        float x0 = bf16f((u16)xw);
        float x1 = bf16f((u16)(xw >> 16));
        float z0 = x0 + xr0; z0 = z0 > 0.f ? z0 : 0.2f * z0;
        float z1 = x1 + xr1; z1 = z1 > 0.f ? z1 : 0.2f * z1;
        float z = fmaf(z0, a0, z1 * a1);
        #pragma unroll
        for (int m = 1; m < 16; m <<= 1)
            z += __shfl_xor(z, m, 64);
        float p = __expf(z);
        s += p;
        acc0 = fmaf(p, x0, acc0);
        acc1 = fmaf(p, x1, acc1);
    }

    float inv = 1.f / s;
    float v0 = acc0 * inv + bias[c];
    float v1 = acc1 * inv + bias[c + 1];
    v0 = v0 > 0.f ? v0 : expm1f(v0);
    v1 = v1 > 0.f ? v1 : expm1f(v1);
    *(u32*)(outp + (size_t)node * 128 + c) = (u32)bf16rne(v0) | ((u32)bf16rne(v1) << 16);
}

// ---------------------------------------------------------------------------
extern "C" void kernel_launch(void* const* d_in, const int* in_sizes, int n_in,
                              void* d_out, int out_size, void* d_ws, size_t ws_size,
                              hipStream_t stream)
{
    const float* x    = (const float*)d_in[0];
    const int*   ei   = (const int*)  d_in[1];
    const float* Wl1  = (const float*)d_in[2];
    const float* Wr1  = (const float*)d_in[3];
    const float* att1 = (const float*)d_in[4];
    const float* b1   = (const float*)d_in[5];
    const float* Wl2  = (const float*)d_in[6];
    const float* Wr2  = (const float*)d_in[7];
    const float* att2 = (const float*)d_in[8];
    const float* b2   = (const float*)d_in[9];
    const float* W1   = (const float*)d_in[10];
    const float* bb1  = (const float*)d_in[11];
    const float* W2   = (const float*)d_in[12];
    const float* bb2  = (const float*)d_in[13];
    const float* W3   = (const float*)d_in[14];
    const float* bb3  = (const float*)d_in[15];
    float* out = (float*)d_out;

    const int Nn   = in_sizes[0] / 128;
    const int E    = in_sizes[1] / 2;
    const int Etot = E + Nn;

    // ---- workspace. Front region (xh 12.8 + xlxr 25.6 + h1 12.8 = 51.2 MB)
    // is dead by MLP time; t1/t2 (CHUNK=25000 -> 48 MB) overlay it. ----
    char* base = (char*)d_ws;
    size_t woff = 0;
    auto alloc = [&](size_t bytes) -> void* {
        woff = (woff + 255) & ~(size_t)255;
        void* p = base + woff;
        woff += bytes;
        return p;
    };
    u16* xh   = (u16*)alloc((size_t)Nn * 128 * 2);
    u16* xlxr = (u16*)alloc((size_t)Nn * 256 * 2);
    u16* h1   = (u16*)alloc((size_t)Nn * 128 * 2);
    u16* h2   = (u16*)alloc((size_t)Nn * 128 * 2);
    u16* WLR1 = (u16*)alloc((size_t)256 * 128 * 2);
    u16* WLR2 = (u16*)alloc((size_t)256 * 128 * 2);
    u16* W1t  = (u16*)alloc((size_t)640 * 128 * 2);
    u16* W2t  = (u16*)alloc((size_t)320 * 640 * 2);
    u16* W3t  = (u16*)alloc((size_t)64 * 320 * 2);
    int* off  = (int*)alloc((size_t)(Nn + 1) * 4);
    int* bsum = (int*)alloc(64 * 4);
    int* deg  = (int*)alloc((size_t)Nn * 4);
    int* csrc = (int*)alloc((size_t)Etot * 4);

    dim3 blk(256);
    auto gemm = [&](const u16* A, const u16* Bt, const float* bias,
                    float* Cf, u16* Cp, int M, int N, int K, int act) {
        dim3 grid(N / BN, (M + BM - 1) / BM);
        hipLaunchKernelGGL(gemm_mfma, grid, blk, 0, stream, A, Bt, bias, Cf, Cp, M, N, K, act);
    };

    const int eb  = (Etot + 255) / 256;
    const int nb  = (Nn + 1023) / 1024;
    const int nb2 = (Nn + 255) / 256;
    const int gatb = (Nn + 3) / 4;

    // ---- CSR build (once) ----
    hipMemsetAsync(deg, 0, (size_t)Nn * sizeof(int), stream);
    hipLaunchKernelGGL(histo_kernel, dim3(eb), blk, 0, stream, ei, E, Etot, deg);
    hipLaunchKernelGGL(scan1_kernel, dim3(nb), blk, 0, stream, deg, off, bsum, Nn);
    hipLaunchKernelGGL(scan2_kernel, dim3(1), dim3(64), 0, stream, bsum, nb, off + Nn);
    hipLaunchKernelGGL(scan3_kernel, dim3(nb2), blk, 0, stream, off, bsum, Nn);
    hipMemsetAsync(deg, 0, (size_t)Nn * sizeof(int), stream);
    hipLaunchKernelGGL(scatter_kernel, dim3(eb), blk, 0, stream, ei, E, Etot, off, deg, csrc);

    // ---- prep: bf16 convert + transposed weights ----
    hipLaunchKernelGGL(xsplit_kernel, dim3((Nn * 128 + 255) / 256), blk, 0, stream, x, xh, Nn * 128);
    hipLaunchKernelGGL(wsplit_conv, dim3(64, 4), blk, 0, stream, Wl1, Wr1, Wl2, Wr2, WLR1, WLR2);
    hipLaunchKernelGGL(wsplit_kernel, dim3((640 + 255) / 256, 128), blk, 0, stream, W1, W1t, 128, 640);
    hipLaunchKernelGGL(wsplit_kernel, dim3((320 + 255) / 256, 640), blk, 0, stream, W2, W2t, 640, 320);
    hipLaunchKernelGGL(wsplit_kernel, dim3((64 + 255) / 256, 320), blk, 0, stream, W3, W3t, 320, 64);

    // ---- conv1 ----
    gemm(xh, WLR1, nullptr, nullptr, xlxr, Nn, 256, 128, 0);
    hipLaunchKernelGGL(gat_fused, dim3(gatb), blk, 0, stream, xlxr, off, csrc, att1, b1, h1, Nn);

    // ---- conv2 ----
    gemm(h1, WLR2, nullptr, nullptr, xlxr, Nn, 256, 128, 0);
    hipLaunchKernelGGL(gat_fused, dim3(gatb), blk, 0, stream, xlxr, off, csrc, att2, b2, h2, Nn);

    // ---- MLP head (t1/t2 overlay dead front region) ----
    const int CHUNK = 25000;
    u16* t1 = (u16*)base;                      // 25000*640*2 = 32 MB
    u16* t2 = t1 + (size_t)CHUNK * 640;        // 25000*320*2 = 16 MB
    for (int c0 = 0; c0 < Nn; c0 += CHUNK) {
        int cm = (Nn - c0) < CHUNK ? (Nn - c0) : CHUNK;
        gemm(h2 + (size_t)c0 * 128, W1t, bb1, nullptr, t1, cm, 640, 128, 1);
        gemm(t1, W2t, bb2, nullptr, t2, cm, 320, 640, 1);
        gemm(t2, W3t, bb3, out + (size_t)c0 * 64, nullptr, cm, 64, 320, 2);
    }
}